// Round 2
// baseline (341.208 us; speedup 1.0000x reference)
//
#include <hip/hip_runtime.h>

#define NHEADS 12
#define SEQ    1024
#define BATCH  4
#define HDIM   768
#define DHEAD  64
#define BH_TOT 48
#define EPSN   1e-6f

typedef __attribute__((ext_vector_type(8))) short bf8;   // 8 bf16 = 4 VGPRs (MFMA A/B frag)
typedef __attribute__((ext_vector_type(4))) short bf4;   // 4 bf16 packed store
typedef __attribute__((ext_vector_type(4))) float fx4;   // MFMA C/D frag / float4

__device__ __forceinline__ float bf2f(unsigned short h) {
  union { unsigned int u; float f; } v; v.u = ((unsigned int)h) << 16; return v.f;
}
__device__ __forceinline__ unsigned short f2bf(float f) {
  union { float f; unsigned int u; } v; v.f = f;
  unsigned int u = v.u;
  return (unsigned short)((u + 0x7FFFu + ((u >> 16) & 1u)) >> 16);
}

// ---------------------------------------------------------------------------
// Projection GEMM: out = X[4096,768] @ W[768,768]^T + b (X,W f32 in global),
// converted to bf16 on the fly, written head-split as bf16.
// z selects (X, W, b, out). z==2 (V) writes transposed: Vt[bh*64+d][1024].
// 128x128 tile, 4 waves (2x2), each wave 64x64 via 4x4 mfma_16x16x32_bf16.
// ---------------------------------------------------------------------------
__global__ __launch_bounds__(256, 2)
void proj_kernel(const float* __restrict__ hs,
                 const float* __restrict__ te,
                 const float* __restrict__ se,
                 const float* __restrict__ Wq, const float* __restrict__ bq,
                 const float* __restrict__ Wk, const float* __restrict__ bk,
                 const float* __restrict__ Wv, const float* __restrict__ bv,
                 const float* __restrict__ Wt, const float* __restrict__ bt,
                 const float* __restrict__ Wsp, const float* __restrict__ bsp,
                 unsigned short* __restrict__ Qb, unsigned short* __restrict__ Kb,
                 unsigned short* __restrict__ Vtb, unsigned short* __restrict__ Tb,
                 unsigned short* __restrict__ Sb)
{
  __shared__ unsigned short Xs[128 * 32];
  __shared__ unsigned short Ys[128 * 32];

  const float *X, *W, *bias;
  unsigned short* out;
  const int z = blockIdx.z;
  if      (z == 0) { X = hs; W = Wq;  bias = bq;  out = Qb;  }
  else if (z == 1) { X = hs; W = Wk;  bias = bk;  out = Kb;  }
  else if (z == 2) { X = hs; W = Wv;  bias = bv;  out = Vtb; }
  else if (z == 3) { X = te; W = Wt;  bias = bt;  out = Tb;  }
  else             { X = se; W = Wsp; bias = bsp; out = Sb;  }

  const int tid   = threadIdx.x;
  const int lane  = tid & 63;
  const int wid   = tid >> 6;
  const int wm    = wid >> 1, wn = wid & 1;
  const int colid = lane & 15, quad = lane >> 4;
  const int m0 = blockIdx.y * 128, n0 = blockIdx.x * 128;

  fx4 acc[4][4];
#pragma unroll
  for (int i = 0; i < 4; ++i)
#pragma unroll
    for (int j = 0; j < 4; ++j) acc[i][j] = (fx4){0.f, 0.f, 0.f, 0.f};

  for (int kt = 0; kt < HDIM; kt += 32) {
    fx4 xa[2][2], wa[2][2];   // slot i, two float4 halves of 8 consecutive floats
#pragma unroll
    for (int i = 0; i < 2; ++i) {
      const int slot = i * 256 + tid;        // 0..511, 8 elems each
      const int row = slot >> 2, ch = slot & 3;
      const float* xp = X + (m0 + row) * HDIM + kt + ch * 8;
      const float* wp = W + (n0 + row) * HDIM + kt + ch * 8;
      xa[i][0] = *(const fx4*)xp;  xa[i][1] = *(const fx4*)(xp + 4);
      wa[i][0] = *(const fx4*)wp;  wa[i][1] = *(const fx4*)(wp + 4);
    }
    __syncthreads();
#pragma unroll
    for (int i = 0; i < 2; ++i) {
      const int slot = i * 256 + tid;
      bf8 xv, wv;
#pragma unroll
      for (int j = 0; j < 8; ++j) {
        xv[j] = (short)f2bf(xa[i][j >> 2][j & 3]);
        wv[j] = (short)f2bf(wa[i][j >> 2][j & 3]);
      }
      *(bf8*)(Xs + slot * 8) = xv;
      *(bf8*)(Ys + slot * 8) = wv;
    }
    __syncthreads();

    bf8 af[4], bfr[4];
#pragma unroll
    for (int i = 0; i < 4; ++i)
      af[i] = *(const bf8*)(Xs + (wm * 64 + i * 16 + colid) * 32 + quad * 8);
#pragma unroll
    for (int j = 0; j < 4; ++j)
      bfr[j] = *(const bf8*)(Ys + (wn * 64 + j * 16 + colid) * 32 + quad * 8);
#pragma unroll
    for (int i = 0; i < 4; ++i)
#pragma unroll
      for (int j = 0; j < 4; ++j)
        acc[i][j] = __builtin_amdgcn_mfma_f32_16x16x32_bf16(af[i], bfr[j], acc[i][j], 0, 0, 0);
  }

  // Epilogue. C row r -> (b, s); col c -> (h, d).  C/D layout: col=lane&15, row=quad*4+reg.
  if (z != 2) {
#pragma unroll
    for (int i = 0; i < 4; ++i) {
      const int r0 = m0 + wm * 64 + i * 16 + quad * 4;   // 4-aligned; b constant over reg
      const int bb = r0 >> 10, s0 = r0 & 1023;
#pragma unroll
      for (int j = 0; j < 4; ++j) {
        const int c = n0 + wn * 64 + j * 16 + colid;
        const int h = c >> 6, d = c & 63;
        const float bvl = bias[c];
        unsigned short* op = out + (((bb * NHEADS + h) * SEQ + s0) * DHEAD + d);
#pragma unroll
        for (int reg = 0; reg < 4; ++reg)
          op[reg * DHEAD] = f2bf(acc[i][j][reg] + bvl);
      }
    }
  } else {
    // V transposed: Vt[(bh*64 + d)*1024 + s]; pack 4 consecutive s per store.
#pragma unroll
    for (int i = 0; i < 4; ++i) {
      const int r0 = m0 + wm * 64 + i * 16 + quad * 4;
      const int bb = r0 >> 10, s0 = r0 & 1023;
#pragma unroll
      for (int j = 0; j < 4; ++j) {
        const int c = n0 + wn * 64 + j * 16 + colid;
        const int h = c >> 6, d = c & 63;
        const float bvl = bias[c];
        bf4 pk;
#pragma unroll
        for (int reg = 0; reg < 4; ++reg)
          pk[reg] = (short)f2bf(acc[i][j][reg] + bvl);
        *(bf4*)(out + ((bb * NHEADS + h) * DHEAD + d) * SEQ + s0) = pk;
      }
    }
  }
}

// ---------------------------------------------------------------------------
// Per-row scale: rs[bh*S+s] = 1 / ((||T_row||+eps) * (||S_row||+eps) * sqrt(64))
// One wave per row (64 lanes = 64 dims), 16 rows per wave.
// ---------------------------------------------------------------------------
__global__ void rowscale_kernel(const unsigned short* __restrict__ Tb,
                                const unsigned short* __restrict__ Sb,
                                float* __restrict__ rs)
{
  const int lane = threadIdx.x & 63;
  const int w = threadIdx.x >> 6;
  const int base = blockIdx.x * 64 + w * 16;
  for (int i = 0; i < 16; ++i) {
    const int row = base + i;
    const float t = bf2f(Tb[row * 64 + lane]);
    const float s = bf2f(Sb[row * 64 + lane]);
    float t2 = t * t, s2 = s * s;
#pragma unroll
    for (int off = 32; off >= 1; off >>= 1) {
      t2 += __shfl_xor(t2, off);
      s2 += __shfl_xor(s2, off);
    }
    if (lane == 0)
      rs[row] = 1.0f / ((sqrtf(t2) + EPSN) * (sqrtf(s2) + EPSN) * 8.0f);
  }
}

// ---------------------------------------------------------------------------
// Flash attention, one wave per 16 q-rows, no barriers.
// scores = (q.k)(T.T)(S.S)*rs + mask ; online softmax ; O += P.V via Vt.
// ---------------------------------------------------------------------------
__global__ __launch_bounds__(256, 2)
void attn_kernel(const unsigned short* __restrict__ Qb,
                 const unsigned short* __restrict__ Kb,
                 const unsigned short* __restrict__ Vtb,
                 const unsigned short* __restrict__ Tb,
                 const unsigned short* __restrict__ Sb,
                 const float* __restrict__ rsb,
                 const float* __restrict__ maskb,
                 float* __restrict__ outb)
{
  __shared__ unsigned short Pls[4][16 * 64];   // per-wave P staging, XOR-swizzled

  const int tid   = threadIdx.x;
  const int lane  = tid & 63;
  const int w     = tid >> 6;
  const int colid = lane & 15, quad = lane >> 4;
  const int bh = blockIdx.y;
  const int b  = bh / NHEADS, h = bh % NHEADS;
  const int q0 = blockIdx.x * 64 + w * 16;
  const int base_h = bh * SEQ * DHEAD;

  // Query-side A-frags (registers, loop-invariant): lane holds A[m=lane&15][k=quad*8+j]
  bf8 aq[2], at[2], asf[2];
  {
    const int row = q0 + colid;
    const unsigned short* qp = Qb + base_h + row * 64 + quad * 8;
    const unsigned short* tp = Tb + base_h + row * 64 + quad * 8;
    const unsigned short* sp = Sb + base_h + row * 64 + quad * 8;
    aq[0]  = *(const bf8*)qp;  aq[1]  = *(const bf8*)(qp + 32);
    at[0]  = *(const bf8*)tp;  at[1]  = *(const bf8*)(tp + 32);
    asf[0] = *(const bf8*)sp;  asf[1] = *(const bf8*)(sp + 32);
  }
  const fx4 rs4 = *(const fx4*)(rsb + bh * SEQ + q0 + quad * 4);

  float m_[4], l_[4];
  fx4 o[4];
#pragma unroll
  for (int r = 0; r < 4; ++r) { m_[r] = -3.0e38f; l_[r] = 0.f; }
#pragma unroll
  for (int fd = 0; fd < 4; ++fd) o[fd] = (fx4){0.f, 0.f, 0.f, 0.f};

  const fx4 zero = (fx4){0.f, 0.f, 0.f, 0.f};
  unsigned short* pw = &Pls[w][0];

  for (int kb = 0; kb < SEQ; kb += 64) {
    float sv[4][4];   // [key-frag][reg]
#pragma unroll
    for (int f = 0; f < 4; ++f) {
      const int key = kb + f * 16 + colid;
      const unsigned short* kp  = Kb + base_h + key * 64 + quad * 8;
      const unsigned short* tp  = Tb + base_h + key * 64 + quad * 8;
      const unsigned short* spp = Sb + base_h + key * 64 + quad * 8;
      const bf8 bk0 = *(const bf8*)kp,  bk1 = *(const bf8*)(kp + 32);
      const bf8 bt0 = *(const bf8*)tp,  bt1 = *(const bf8*)(tp + 32);
      const bf8 bs0 = *(const bf8*)spp, bs1 = *(const bf8*)(spp + 32);
      fx4 ab = __builtin_amdgcn_mfma_f32_16x16x32_bf16(aq[0], bk0, zero, 0, 0, 0);
      ab = __builtin_amdgcn_mfma_f32_16x16x32_bf16(aq[1], bk1, ab, 0, 0, 0);
      fx4 tt = __builtin_amdgcn_mfma_f32_16x16x32_bf16(at[0], bt0, zero, 0, 0, 0);
      tt = __builtin_amdgcn_mfma_f32_16x16x32_bf16(at[1], bt1, tt, 0, 0, 0);
      fx4 ss = __builtin_amdgcn_mfma_f32_16x16x32_bf16(asf[0], bs0, zero, 0, 0, 0);
      ss = __builtin_amdgcn_mfma_f32_16x16x32_bf16(asf[1], bs1, ss, 0, 0, 0);
      const float mk = maskb[b * SEQ + kb + f * 16 + colid];
#pragma unroll
      for (int reg = 0; reg < 4; ++reg)
        sv[f][reg] = ab[reg] * tt[reg] * ss[reg] * rs4[reg] + mk;
    }

    // Online softmax. Row (quad*4+reg) is spread over the 16 lanes of this quad.
#pragma unroll
    for (int reg = 0; reg < 4; ++reg) {
      float rm = fmaxf(fmaxf(sv[0][reg], sv[1][reg]), fmaxf(sv[2][reg], sv[3][reg]));
      rm = fmaxf(rm, __shfl_xor(rm, 1));
      rm = fmaxf(rm, __shfl_xor(rm, 2));
      rm = fmaxf(rm, __shfl_xor(rm, 4));
      rm = fmaxf(rm, __shfl_xor(rm, 8));
      const float mn = fmaxf(m_[reg], rm);
      const float alpha = __expf(m_[reg] - mn);
      float rsum = 0.f;
#pragma unroll
      for (int f = 0; f < 4; ++f) {
        const float p = __expf(sv[f][reg] - mn);
        sv[f][reg] = p;
        rsum += p;
      }
      rsum += __shfl_xor(rsum, 1);
      rsum += __shfl_xor(rsum, 2);
      rsum += __shfl_xor(rsum, 4);
      rsum += __shfl_xor(rsum, 8);
      l_[reg] = l_[reg] * alpha + rsum;
      m_[reg] = mn;
#pragma unroll
      for (int fd = 0; fd < 4; ++fd) o[fd][reg] *= alpha;
    }

    // P (C-layout) -> LDS, XOR-swizzled on 8-elem chunks to kill A-read conflicts.
#pragma unroll
    for (int f = 0; f < 4; ++f) {
      const int col = f * 16 + colid;
      const int c = col >> 3, ci = col & 7;
#pragma unroll
      for (int reg = 0; reg < 4; ++reg) {
        const int row = quad * 4 + reg;
        pw[row * 64 + ((c ^ (row & 7)) << 3) + ci] = f2bf(sv[f][reg]);
      }
    }
    // P A-frags (same wave wrote them; LDS pipe is in-order per wave).
    const int mr = colid;
    const bf8 pa0 = *(const bf8*)(pw + mr * 64 + ((quad ^ (mr & 7)) << 3));
    const bf8 pa1 = *(const bf8*)(pw + mr * 64 + (((4 + quad) ^ (mr & 7)) << 3));

    // O += P.V ; B-frag from transposed V in global: Vt[d][key], contiguous in key.
#pragma unroll
    for (int fd = 0; fd < 4; ++fd) {
      const int d = fd * 16 + colid;
      const unsigned short* vp = Vtb + (bh * DHEAD + d) * SEQ + kb + quad * 8;
      const bf8 bv0 = *(const bf8*)vp;
      const bf8 bv1 = *(const bf8*)(vp + 32);
      o[fd] = __builtin_amdgcn_mfma_f32_16x16x32_bf16(pa0, bv0, o[fd], 0, 0, 0);
      o[fd] = __builtin_amdgcn_mfma_f32_16x16x32_bf16(pa1, bv1, o[fd], 0, 0, 0);
    }
  }

  // Epilogue: out[b, s, h*64+d] = O / l   (float32 output)
#pragma unroll
  for (int reg = 0; reg < 4; ++reg) {
    const int s = q0 + quad * 4 + reg;
    const float inv = 1.0f / l_[reg];
#pragma unroll
    for (int fd = 0; fd < 4; ++fd) {
      const int d = fd * 16 + colid;
      outb[(b * SEQ + s) * HDIM + h * DHEAD + d] = o[fd][reg] * inv;
    }
  }
}

extern "C" void kernel_launch(void* const* d_in, const int* in_sizes, int n_in,
                              void* d_out, int out_size, void* d_ws, size_t ws_size,
                              hipStream_t stream)
{
  (void)in_sizes; (void)n_in; (void)out_size; (void)ws_size;
  const float* hs   = (const float*)d_in[0];
  const float* te   = (const float*)d_in[1];
  const float* se   = (const float*)d_in[2];
  const float* mask = (const float*)d_in[3];
  const float* Wq   = (const float*)d_in[4];
  const float* bq   = (const float*)d_in[5];
  const float* Wk   = (const float*)d_in[6];
  const float* bk   = (const float*)d_in[7];
  const float* Wv   = (const float*)d_in[8];
  const float* bv   = (const float*)d_in[9];
  const float* Wt   = (const float*)d_in[10];
  const float* bt   = (const float*)d_in[11];
  const float* Wsp  = (const float*)d_in[12];
  const float* bsp  = (const float*)d_in[13];
  float* out = (float*)d_out;

  const size_t SZ = (size_t)BH_TOT * SEQ * DHEAD;   // 3,145,728 elems per tensor
  unsigned short* ws  = (unsigned short*)d_ws;
  unsigned short* Qb  = ws;
  unsigned short* Kb  = ws + SZ;
  unsigned short* Vtb = ws + 2 * SZ;
  unsigned short* Tb  = ws + 3 * SZ;
  unsigned short* Sb  = ws + 4 * SZ;
  float* rs = (float*)(ws + 5 * SZ);                // +192 KB, 16B-aligned

  proj_kernel<<<dim3(6, 32, 5), 256, 0, stream>>>(hs, te, se, Wq, bq, Wk, bk, Wv, bv,
                                                  Wt, bt, Wsp, bsp, Qb, Kb, Vtb, Tb, Sb);
  rowscale_kernel<<<dim3(768), 256, 0, stream>>>(Tb, Sb, rs);
  attn_kernel<<<dim3(16, 48), 256, 0, stream>>>(Qb, Kb, Vtb, Tb, Sb, rs, mask, out);
}